// Round 3
// baseline (596.611 us; speedup 1.0000x reference)
//
#include <hip/hip_runtime.h>
#include <math.h>

#define NA 16
#define NBEAM 12
#define NUSER 8

// ws layout: [0 .. 1535]  : steering table, 12 beams x (16 cos | 16 sin) floats
//            [1536..1543] : double accumulator
#define ACC_OFFSET 1536

__global__ void mtl_angles_kernel(const float* __restrict__ Hc_r, const float* __restrict__ Hc_i,
                                  const float* __restrict__ Hs_r, const float* __restrict__ Hs_i,
                                  float* __restrict__ table, double* __restrict__ acc) {
    int t = threadIdx.x;
    if (t == 0) *acc = 0.0;          // zero the reduction accumulator (ws is poisoned 0xAA)
    if (t >= NBEAM) return;

    const float* re;
    const float* im;
    if (t < NUSER) { re = Hc_r + t * NA;           im = Hc_i + t * NA; }          // Hc[0, t, :]
    else           { re = Hs_r + (t - NUSER) * NA; im = Hs_i + (t - NUSER) * NA; } // Hs[0, t, :]

    const float PI_F   = 3.14159265358979323846f;
    const float TWO_PI = 6.28318530717958647692f;

    float ph[NA];
    #pragma unroll
    for (int n = 0; n < NA; ++n) ph[n] = atan2f(im[n], re[n]);

    // unwrapped[0]=0; unwrapped[n]=cumsum of wrapped diffs. n_c = n - 7.5, sum(n_c^2)=340.
    float unw = 0.f, dotsum = 0.f;
    #pragma unroll
    for (int n = 1; n < NA; ++n) {
        float pd = ph[n] - ph[n - 1];
        float x  = pd + PI_F;
        float m  = fmodf(x, TWO_PI);       // python % has sign of divisor
        if (m < 0.f) m += TWO_PI;
        pd = m - PI_F;
        unw += pd;
        dotsum += unw * ((float)n - 7.5f);
    }
    float slope = dotsum / 340.0f;
    float sin_theta = slope / PI_F;        // slope * WAVELENGTH / (2*pi*D), D=0.5, lambda=1
    sin_theta = fminf(1.0f, fmaxf(-1.0f, sin_theta));
    // angle = -asin(sin_theta); steering uses sin(angle) = -sin_theta
    float st = -sin_theta;

    #pragma unroll
    for (int n = 0; n < NA; ++n) {
        float phase = PI_F * st * (float)n;    // 2*pi*D*st*n/lambda = pi*st*n
        table[t * 2 * NA + n]      = cosf(phase);
        table[t * 2 * NA + NA + n] = sinf(phase);
    }
}

__device__ __forceinline__ float dot4(float4 a, float4 b) {
    return a.x * b.x + a.y * b.y + a.z * b.z + a.w * b.w;
}

// Async global->LDS, 16 B per lane. LDS dest is wave-uniform base + lane*16.
__device__ __forceinline__ void load_lds16(const float* g, float* l) {
    __builtin_amdgcn_global_load_lds(
        (const __attribute__((address_space(1))) void*)g,
        (__attribute__((address_space(3))) void*)l, 16, 0, 0);
}

// Per-row loss contribution given the row's 8 float4s and the shared table.
__device__ __forceinline__ float row_loss(const float4* w, const float* tbs) {
    float minU = 3.4e38f, sumU = 0.f, sumT = 0.f;
    #pragma unroll 1
    for (int j = 0; j < NBEAM; ++j) {
        const float4* tc = (const float4*)(tbs + j * 32);
        float re = 0.f, im = 0.f;
        #pragma unroll
        for (int q = 0; q < 4; ++q) {
            float4 c = tc[q], s = tc[q + 4];
            float4 wr = w[q], wi = w[q + 4];
            re += dot4(wr, c) + dot4(wi, s);
            im += dot4(wi, c) - dot4(wr, s);
        }
        float g = sqrtf(re * re + im * im);
        if (j < NUSER) { minU = fminf(minU, g); sumU += g; }
        else           { sumT += g; }
    }
    // comm = -rho*2.5*(min + 0.1*sum) = -2*(min+0.1*sum); sens = -(1-rho)*sumT/4 = -0.05*sumT
    return -2.0f * (minU + 0.1f * sumU) - 0.05f * sumT;
}

// R2 post-mortem: one-row-per-thread global loads scatter each dwordx4 over
// 64 cache lines (lane stride 128 B). Fix: coalesced global->LDS tile staging
// (global_load_lds, width 16) + rotated-quad LDS reads (q=(t+i)&7) so each
// ds_read_b128 spreads lanes across all 32 banks (8 dwords/bank = wave64 min).
__global__ __launch_bounds__(256, 4) void mtl_gains_kernel(const float* __restrict__ W,
                                                           const float* __restrict__ table,
                                                           double* __restrict__ acc, int rows) {
    __shared__ float sh[256 * 32];          // 32 KB: 256 rows x 128 B, packed
    __shared__ float tbs[NBEAM * 2 * NA];   // steering table, 384 floats
    __shared__ float wsum[4];

    for (int i = threadIdx.x; i < NBEAM * 2 * NA; i += blockDim.x) tbs[i] = table[i];
    __syncthreads();

    const int t = threadIdx.x;
    const int wave_base = (t & 192) * 4;    // (t>>6)*64 lanes * 4 floats of f4 = wave-uniform
    float local = 0.f;

    const int ntiles = rows >> 8;           // full 256-row tiles
    #pragma unroll 1
    for (int tile = blockIdx.x; tile < ntiles; tile += gridDim.x) {
        const float* gW = W + (size_t)tile * 256 * 32;
        // Stage 256 rows (32 KB) coalesced: f4 index k = i*256 + t lands at LDS
        // byte offset k*16 (dest = wave-uniform base + lane*16).
        #pragma unroll
        for (int i = 0; i < 8; ++i) {
            int k = i * 256 + t;
            load_lds16(gW + 4 * k, sh + i * 1024 + wave_base);
        }
        __syncthreads();   // drains vmcnt before barrier (compiler-enforced)

        // Each thread owns tile-row t; rotated quad order avoids bank conflicts.
        const float4* myrow = (const float4*)(sh + t * 32);
        float4 w[8];
        #pragma unroll
        for (int i = 0; i < 8; ++i) {
            int q = (t + i) & 7;
            w[q] = myrow[q];
        }
        local += row_loss(w, tbs);
        __syncthreads();
    }

    // Tail rows (rows % 256) via direct global loads in block 0.
    int tailbase = ntiles << 8;
    if (blockIdx.x == 0) {
        int row = tailbase + t;
        if (row < rows) {
            const float4* wp = (const float4*)(W + (size_t)row * 32);
            float4 w[8];
            #pragma unroll
            for (int i = 0; i < 8; ++i) w[i] = wp[i];
            local += row_loss(w, tbs);
        }
    }

    // wave reduce (64 lanes)
    #pragma unroll
    for (int off = 32; off > 0; off >>= 1) local += __shfl_down(local, off);
    int lane = threadIdx.x & 63, wid = threadIdx.x >> 6;
    if (lane == 0) wsum[wid] = local;
    __syncthreads();
    if (threadIdx.x == 0) {
        float b = wsum[0] + wsum[1] + wsum[2] + wsum[3];
        atomicAdd(acc, (double)b);
    }
}

__global__ void mtl_finalize_kernel(const double* __restrict__ acc, float* __restrict__ out, int rows) {
    if (threadIdx.x == 0) out[0] = (float)(*acc / (double)rows);
}

extern "C" void kernel_launch(void* const* d_in, const int* in_sizes, int n_in,
                              void* d_out, int out_size, void* d_ws, size_t ws_size,
                              hipStream_t stream) {
    const float* W    = (const float*)d_in[0];
    const float* Hc_r = (const float*)d_in[1];
    const float* Hc_i = (const float*)d_in[2];
    const float* Hs_r = (const float*)d_in[3];
    const float* Hs_i = (const float*)d_in[4];
    float* out = (float*)d_out;

    int rows = in_sizes[0] / (2 * NA);   // 2,000,000
    float*  table = (float*)d_ws;
    double* acc   = (double*)((char*)d_ws + ACC_OFFSET);

    mtl_angles_kernel<<<1, 64, 0, stream>>>(Hc_r, Hc_i, Hs_r, Hs_i, table, acc);

    int ntiles = rows >> 8;
    int blocks = ntiles < 1024 ? (ntiles > 0 ? ntiles : 1) : 1024;
    mtl_gains_kernel<<<blocks, 256, 0, stream>>>(W, table, acc, rows);

    mtl_finalize_kernel<<<1, 64, 0, stream>>>(acc, out, rows);
}

// Round 4
// 369.749 us; speedup vs baseline: 1.6136x; 1.6136x over previous
//
#include <hip/hip_runtime.h>
#include <math.h>

#define NA 16
#define NBEAM 12
#define NUSER 8

// ws layout: [0 .. 1535]  : steering table, 12 beams x (16 cos | 16 sin) floats
//            [1536..1543] : double accumulator
#define ACC_OFFSET 1536

__global__ void mtl_angles_kernel(const float* __restrict__ Hc_r, const float* __restrict__ Hc_i,
                                  const float* __restrict__ Hs_r, const float* __restrict__ Hs_i,
                                  float* __restrict__ table, double* __restrict__ acc) {
    int t = threadIdx.x;
    if (t == 0) *acc = 0.0;          // zero the reduction accumulator (ws is poisoned 0xAA)
    if (t >= NBEAM) return;

    const float* re;
    const float* im;
    if (t < NUSER) { re = Hc_r + t * NA;           im = Hc_i + t * NA; }          // Hc[0, t, :]
    else           { re = Hs_r + (t - NUSER) * NA; im = Hs_i + (t - NUSER) * NA; } // Hs[0, t, :]

    const float PI_F   = 3.14159265358979323846f;
    const float TWO_PI = 6.28318530717958647692f;

    float ph[NA];
    #pragma unroll
    for (int n = 0; n < NA; ++n) ph[n] = atan2f(im[n], re[n]);

    // unwrapped[0]=0; unwrapped[n]=cumsum of wrapped diffs. n_c = n - 7.5, sum(n_c^2)=340.
    float unw = 0.f, dotsum = 0.f;
    #pragma unroll
    for (int n = 1; n < NA; ++n) {
        float pd = ph[n] - ph[n - 1];
        float x  = pd + PI_F;
        float m  = fmodf(x, TWO_PI);       // python % has sign of divisor
        if (m < 0.f) m += TWO_PI;
        pd = m - PI_F;
        unw += pd;
        dotsum += unw * ((float)n - 7.5f);
    }
    float slope = dotsum / 340.0f;
    float sin_theta = slope / PI_F;        // slope * WAVELENGTH / (2*pi*D), D=0.5, lambda=1
    sin_theta = fminf(1.0f, fmaxf(-1.0f, sin_theta));
    // angle = -asin(sin_theta); steering uses sin(angle) = -sin_theta
    float st = -sin_theta;

    #pragma unroll
    for (int n = 0; n < NA; ++n) {
        float phase = PI_F * st * (float)n;    // 2*pi*D*st*n/lambda = pi*st*n
        table[t * 2 * NA + n]      = cosf(phase);
        table[t * 2 * NA + NA + n] = sinf(phase);
    }
}

__device__ __forceinline__ float dot4(float4 a, float4 b) {
    return a.x * b.x + a.y * b.y + a.z * b.z + a.w * b.w;
}

// Loss contributions of two rows, sharing each beam's 8 table float4s.
// (Halves LDS broadcast traffic per row vs one-row-at-a-time.)
__device__ __forceinline__ float2 pair_loss(const float4* wa, const float4* wb,
                                            const float* tbs) {
    float minU0 = 3.4e38f, sumU0 = 0.f, sumT0 = 0.f;
    float minU1 = 3.4e38f, sumU1 = 0.f, sumT1 = 0.f;
    #pragma unroll 1
    for (int j = 0; j < NBEAM; ++j) {
        const float4* tc = (const float4*)(tbs + j * 32);
        float re0 = 0.f, im0 = 0.f, re1 = 0.f, im1 = 0.f;
        #pragma unroll
        for (int q = 0; q < 4; ++q) {
            float4 c = tc[q], s = tc[q + 4];
            float4 ar = wa[q], ai = wa[q + 4];
            float4 br = wb[q], bi = wb[q + 4];
            re0 += dot4(ar, c) + dot4(ai, s);
            im0 += dot4(ai, c) - dot4(ar, s);
            re1 += dot4(br, c) + dot4(bi, s);
            im1 += dot4(bi, c) - dot4(br, s);
        }
        float g0 = sqrtf(re0 * re0 + im0 * im0);
        float g1 = sqrtf(re1 * re1 + im1 * im1);
        if (j < NUSER) { minU0 = fminf(minU0, g0); sumU0 += g0;
                         minU1 = fminf(minU1, g1); sumU1 += g1; }
        else           { sumT0 += g0; sumT1 += g1; }
    }
    // comm = -rho*2.5*(min + 0.1*sum) = -2*(min+0.1*sum); sens = -(1-rho)*sumT/4 = -0.05*sumT
    return make_float2(-2.0f * (minU0 + 0.1f * sumU0) - 0.05f * sumT0,
                       -2.0f * (minU1 + 0.1f * sumU1) - 0.05f * sumT1);
}

// R3 post-mortem: synchronous LDS tile staging killed MLP (barrier-drained
// vmcnt each tile) and hit 8-way bank conflicts (row stride 128 B = 32 banks).
// R4: back to direct per-thread loads (R2 structure, ~115 us), plus:
//  - block-contiguous chunks (each iteration reads a contiguous 64 KB window)
//  - 2 rows per thread per beam pass (halves table LDS reads per row, 16
//    dwordx4 in flight per thread per wait)
__global__ __launch_bounds__(256, 4) void mtl_gains_kernel(const float* __restrict__ W,
                                                           const float* __restrict__ table,
                                                           double* __restrict__ acc, int rows) {
    __shared__ float tbs[NBEAM * 2 * NA];   // steering table, 384 floats
    __shared__ float wsum[4];
    for (int i = threadIdx.x; i < NBEAM * 2 * NA; i += blockDim.x) tbs[i] = table[i];
    __syncthreads();

    const int t = threadIdx.x;
    const int ROWS_PER_BLOCK = 2048;        // 4 iterations x 512 rows
    const int base = blockIdx.x * ROWS_PER_BLOCK + t;

    float local = 0.f;
    #pragma unroll 1
    for (int k = 0; k < 4; ++k) {
        int rowA = base + k * 512;
        int rowB = rowA + 256;
        size_t ra = (size_t)(rowA < rows ? rowA : rows - 1);
        size_t rb = (size_t)(rowB < rows ? rowB : rows - 1);
        const float4* pa = (const float4*)(W + ra * 32);
        const float4* pb = (const float4*)(W + rb * 32);
        float4 wa[8], wb[8];
        #pragma unroll
        for (int i = 0; i < 8; ++i) wa[i] = pa[i];
        #pragma unroll
        for (int i = 0; i < 8; ++i) wb[i] = pb[i];

        float2 v = pair_loss(wa, wb, tbs);
        if (rowA < rows) local += v.x;
        if (rowB < rows) local += v.y;
    }

    // wave reduce (64 lanes)
    #pragma unroll
    for (int off = 32; off > 0; off >>= 1) local += __shfl_down(local, off);
    int lane = threadIdx.x & 63, wid = threadIdx.x >> 6;
    if (lane == 0) wsum[wid] = local;
    __syncthreads();
    if (threadIdx.x == 0) {
        float b = wsum[0] + wsum[1] + wsum[2] + wsum[3];
        atomicAdd(acc, (double)b);
    }
}

__global__ void mtl_finalize_kernel(const double* __restrict__ acc, float* __restrict__ out, int rows) {
    if (threadIdx.x == 0) out[0] = (float)(*acc / (double)rows);
}

extern "C" void kernel_launch(void* const* d_in, const int* in_sizes, int n_in,
                              void* d_out, int out_size, void* d_ws, size_t ws_size,
                              hipStream_t stream) {
    const float* W    = (const float*)d_in[0];
    const float* Hc_r = (const float*)d_in[1];
    const float* Hc_i = (const float*)d_in[2];
    const float* Hs_r = (const float*)d_in[3];
    const float* Hs_i = (const float*)d_in[4];
    float* out = (float*)d_out;

    int rows = in_sizes[0] / (2 * NA);   // 2,000,000
    float*  table = (float*)d_ws;
    double* acc   = (double*)((char*)d_ws + ACC_OFFSET);

    mtl_angles_kernel<<<1, 64, 0, stream>>>(Hc_r, Hc_i, Hs_r, Hs_i, table, acc);

    int blocks = (rows + 2047) / 2048;   // 977 blocks, all resident (~3.8/CU)
    mtl_gains_kernel<<<blocks, 256, 0, stream>>>(W, table, acc, rows);

    mtl_finalize_kernel<<<1, 64, 0, stream>>>(acc, out, rows);
}

// Round 5
// 362.485 us; speedup vs baseline: 1.6459x; 1.0200x over previous
//
#include <hip/hip_runtime.h>
#include <math.h>

#define NA 16
#define NBEAM 12
#define NUSER 8

// ws layout: [0 .. 1535]  : steering table, 12 beams x (16 cos | 16 sin) floats
//            [1536..1543] : double accumulator
#define ACC_OFFSET 1536

__global__ void mtl_angles_kernel(const float* __restrict__ Hc_r, const float* __restrict__ Hc_i,
                                  const float* __restrict__ Hs_r, const float* __restrict__ Hs_i,
                                  float* __restrict__ table, double* __restrict__ acc) {
    int t = threadIdx.x;
    if (t == 0) *acc = 0.0;          // zero the reduction accumulator (ws is poisoned 0xAA)
    if (t >= NBEAM) return;

    const float* re;
    const float* im;
    if (t < NUSER) { re = Hc_r + t * NA;           im = Hc_i + t * NA; }          // Hc[0, t, :]
    else           { re = Hs_r + (t - NUSER) * NA; im = Hs_i + (t - NUSER) * NA; } // Hs[0, t, :]

    const float PI_F   = 3.14159265358979323846f;
    const float TWO_PI = 6.28318530717958647692f;

    float ph[NA];
    #pragma unroll
    for (int n = 0; n < NA; ++n) ph[n] = atan2f(im[n], re[n]);

    // unwrapped[0]=0; unwrapped[n]=cumsum of wrapped diffs. n_c = n - 7.5, sum(n_c^2)=340.
    float unw = 0.f, dotsum = 0.f;
    #pragma unroll
    for (int n = 1; n < NA; ++n) {
        float pd = ph[n] - ph[n - 1];
        float x  = pd + PI_F;
        float m  = fmodf(x, TWO_PI);       // python % has sign of divisor
        if (m < 0.f) m += TWO_PI;
        pd = m - PI_F;
        unw += pd;
        dotsum += unw * ((float)n - 7.5f);
    }
    float slope = dotsum / 340.0f;
    float sin_theta = slope / PI_F;        // slope * WAVELENGTH / (2*pi*D), D=0.5, lambda=1
    sin_theta = fminf(1.0f, fmaxf(-1.0f, sin_theta));
    // angle = -asin(sin_theta); steering uses sin(angle) = -sin_theta
    float st = -sin_theta;

    #pragma unroll
    for (int n = 0; n < NA; ++n) {
        float phase = PI_F * st * (float)n;    // 2*pi*D*st*n/lambda = pi*st*n
        table[t * 2 * NA + n]      = cosf(phase);
        table[t * 2 * NA + NA + n] = sinf(phase);
    }
}

__device__ __forceinline__ float dot4(float4 a, float4 b) {
    return a.x * b.x + a.y * b.y + a.z * b.z + a.w * b.w;
}

// Async global->LDS, 16 B per lane. LDS dest is wave-uniform base + lane*16.
__device__ __forceinline__ void load_lds16(const float* g, float* l) {
    __builtin_amdgcn_global_load_lds(
        (const __attribute__((address_space(1))) void*)g,
        (__attribute__((address_space(3))) void*)l, 16, 0, 0);
}

// Per-row loss contribution given the row's 8 float4s and the shared table.
__device__ __forceinline__ float row_loss(const float4* w, const float* tbs) {
    float minU = 3.4e38f, sumU = 0.f, sumT = 0.f;
    #pragma unroll 1
    for (int j = 0; j < NBEAM; ++j) {
        const float4* tc = (const float4*)(tbs + j * 32);
        float re = 0.f, im = 0.f;
        #pragma unroll
        for (int q = 0; q < 4; ++q) {
            float4 c = tc[q], s = tc[q + 4];
            float4 wr = w[q], wi = w[q + 4];
            re += dot4(wr, c) + dot4(wi, s);
            im += dot4(wi, c) - dot4(wr, s);
        }
        float g = sqrtf(re * re + im * im);
        if (j < NUSER) { minU = fminf(minU, g); sumU += g; }
        else           { sumT += g; }
    }
    // comm = -rho*2.5*(min + 0.1*sum) = -2*(min+0.1*sum); sens = -(1-rho)*sumT/4 = -0.05*sumT
    return -2.0f * (minU + 0.1f * sumU) - 0.05f * sumT;
}

// R5: per-wave double-buffered LDS staging, no barriers in the loop.
//  - Coalesced staging: global_load_lds width 16, lane stride 16 B (fixes the
//    4x line-request rate of thread-per-row direct loads = R4's ~2 TB/s cap).
//  - XOR swizzle ON THE GLOBAL SOURCE (LDS dest must stay contiguous): LDS
//    slot row*8+q holds global quad row*8+(q^(row&7)). Read step q touches
//    banks 4*(q^(lane&7))..+3 -> all 32 banks, 8/bank = b128 minimum. Fixes
//    R3's 1e6 bank-conflict cycles.
//  - Per-wave tiles (64 rows = 8 KB) + own vmcnt: asm s_waitcnt vmcnt(8)
//    keeps the next tile's 8 loads in flight during compute; no __syncthreads
//    drain (R3's other killer).
__global__ __launch_bounds__(256, 2) void mtl_gains_kernel(const float* __restrict__ W,
                                                           const float* __restrict__ table,
                                                           double* __restrict__ acc, int rows) {
    __shared__ float sh[4 * 2 * 2048];      // 64 KB: 4 waves x 2 buffers x 8 KB
    __shared__ float tbs[NBEAM * 2 * NA];   // steering table, 384 floats
    __shared__ float wsum[4];

    const int t = threadIdx.x;
    for (int i = t; i < NBEAM * 2 * NA; i += blockDim.x) tbs[i] = table[i];
    __syncthreads();

    const int wid  = t >> 6;
    const int lane = t & 63;
    float* buf0 = sh + wid * 4096;
    float* buf1 = buf0 + 2048;

    // k-independent swizzled source offset: staging instr k, lane -> LDS slot
    // p = k*64+lane; row(p)=k*8+(lane>>3), q(p)=lane&7; source quad =
    // row*8 + ((lane&7) ^ ((lane>>3)&7)).
    const int sq      = (lane & 7) ^ ((lane >> 3) & 7);
    const int src_off = (lane >> 3) * 32 + sq * 4;     // floats within the tile

    const int ntiles    = rows >> 6;                    // 64-row tiles (31250)
    const int nwaves    = gridDim.x * 4;
    const int gw        = blockIdx.x * 4 + wid;
    const int base_cnt  = ntiles / nwaves;
    const int rem       = ntiles % nwaves;
    const int t0        = gw * base_cnt + (gw < rem ? gw : rem);
    const int t1        = t0 + base_cnt + (gw < rem ? 1 : 0);

    float local = 0.f;

    if (t0 < t1) {
        // prologue: stage tile t0 into buf0
        {
            const float* src = W + (size_t)t0 * 2048 + src_off;
            #pragma unroll
            for (int k = 0; k < 8; ++k) load_lds16(src + k * 256, buf0 + k * 256);
        }
        #pragma unroll 1
        for (int tt = t0; tt < t1; ++tt) {
            float* cur = ((tt - t0) & 1) ? buf1 : buf0;
            float* nxt = ((tt - t0) & 1) ? buf0 : buf1;
            if (tt + 1 < t1) {
                const float* src = W + (size_t)(tt + 1) * 2048 + src_off;
                #pragma unroll
                for (int k = 0; k < 8; ++k) load_lds16(src + k * 256, nxt + k * 256);
                // 16 staging loads outstanding; wait for tile tt's 8 (oldest),
                // keep tile tt+1's 8 in flight through the compute below.
                asm volatile("s_waitcnt vmcnt(8)" ::: "memory");
            } else {
                asm volatile("s_waitcnt vmcnt(0)" ::: "memory");
            }

            const float* myrow = cur + lane * 32;      // my row, swizzled quads
            float4 w[8];
            #pragma unroll
            for (int q = 0; q < 8; ++q) {
                int s = q ^ (lane & 7);
                w[q] = *(const float4*)(myrow + s * 4);
            }
            local += row_loss(w, tbs);
        }
    }

    // generic tail (rows % 64) — zero iterations for rows = 2,000,000
    int tailbase = ntiles << 6;
    if (blockIdx.x == 0) {
        int row = tailbase + t;
        if (row < rows) {
            const float4* wp = (const float4*)(W + (size_t)row * 32);
            float4 w[8];
            #pragma unroll
            for (int i = 0; i < 8; ++i) w[i] = wp[i];
            local += row_loss(w, tbs);
        }
    }

    // wave reduce (64 lanes)
    #pragma unroll
    for (int off = 32; off > 0; off >>= 1) local += __shfl_down(local, off);
    if (lane == 0) wsum[wid] = local;
    __syncthreads();
    if (t == 0) {
        float b = wsum[0] + wsum[1] + wsum[2] + wsum[3];
        atomicAdd(acc, (double)b);
    }
}

__global__ void mtl_finalize_kernel(const double* __restrict__ acc, float* __restrict__ out, int rows) {
    if (threadIdx.x == 0) out[0] = (float)(*acc / (double)rows);
}

extern "C" void kernel_launch(void* const* d_in, const int* in_sizes, int n_in,
                              void* d_out, int out_size, void* d_ws, size_t ws_size,
                              hipStream_t stream) {
    const float* W    = (const float*)d_in[0];
    const float* Hc_r = (const float*)d_in[1];
    const float* Hc_i = (const float*)d_in[2];
    const float* Hs_r = (const float*)d_in[3];
    const float* Hs_i = (const float*)d_in[4];
    float* out = (float*)d_out;

    int rows = in_sizes[0] / (2 * NA);   // 2,000,000
    float*  table = (float*)d_ws;
    double* acc   = (double*)((char*)d_ws + ACC_OFFSET);

    mtl_angles_kernel<<<1, 64, 0, stream>>>(Hc_r, Hc_i, Hs_r, Hs_i, table, acc);

    // 512 blocks x 4 waves = 2048 waves, exactly 2 blocks/CU resident (64 KB LDS each)
    mtl_gains_kernel<<<512, 256, 0, stream>>>(W, table, acc, rows);

    mtl_finalize_kernel<<<1, 64, 0, stream>>>(acc, out, rows);
}